// Round 7
// baseline (3513.478 us; speedup 1.0000x reference)
//
#include <hip/hip_runtime.h>
#include <hip/hip_bf16.h>
#include <cstdint>

// ---------------------------------------------------------------------------
// BitLinear GLU: x[8192,2048] f32, W[8192,2048] f32 -> out[8192,4096] f32
//   Identity: out = (normed @ w_bin^T) * w_gamma  -- input_gamma cancels
//   K1: per-row LN (1 wave/row, shfl-only) -> f16  ||  |W| partial sums
//   K2: reduce partials -> wg; w_bin = clip(round(W/(wg+1e-7)),-1,1) (f16)
//   K3: dual-GEMM. R7 structure: A fragments load DIRECT from global (L2-
//       served; frag = contiguous 16B of row-major qA) -- A never touches
//       LDS. LDS holds only B (32KB/tile dbuf = 64KB) -> 2 blocks/CU and
//       -37% LDS-port traffic (the R6-measured binding pipe). 1 barrier and
//       counted vmcnt(4) per K-tile; B staged one tile ahead.
// ---------------------------------------------------------------------------

#define N_TOK   8192
#define DIMIN   2048
#define DIMOUT  8192
#define NOUT    4096   // DIMOUT/2
#define W_ELEMS 16777216.0f
#define NPART   1024
#define NLNB    2048   // LN blocks: 4 rows per block, 1 wave per row

typedef _Float16 f16x8 __attribute__((ext_vector_type(8)));
typedef _Float16 f16x4 __attribute__((ext_vector_type(4)));
typedef float    f32x4 __attribute__((ext_vector_type(4)));

// ---------------- K1: LN rows (wave-per-row) || |W| partial sums ------------
__global__ __launch_bounds__(256) void ln_wsum_k(
    const float* __restrict__ x, const float* __restrict__ w,
    _Float16* __restrict__ qA, float* __restrict__ wpart) {
    const int b = blockIdx.x;
    const int t = threadIdx.x;
    if (b < NLNB) {
        // 4 rows per block, one wave each: no LDS, no __syncthreads.
        const int wv  = t >> 6;
        const int ln  = t & 63;
        const int row = (b << 2) + wv;
        const float4* xr = (const float4*)(x + (size_t)row * DIMIN);
        float4 v[8];
#pragma unroll
        for (int j = 0; j < 4; ++j) {
            v[2 * j]     = xr[2 * ln + 128 * j];
            v[2 * j + 1] = xr[2 * ln + 128 * j + 1];
        }
        float s = 0.0f;
#pragma unroll
        for (int j = 0; j < 8; ++j) s += (v[j].x + v[j].y) + (v[j].z + v[j].w);
#pragma unroll
        for (int o = 32; o > 0; o >>= 1) s += __shfl_xor(s, o, 64);
        const float mu = s * (1.0f / DIMIN);

        float ss = 0.0f;
#pragma unroll
        for (int j = 0; j < 8; ++j) {
            float d0 = v[j].x - mu, d1 = v[j].y - mu;
            float d2 = v[j].z - mu, d3 = v[j].w - mu;
            ss += (d0 * d0 + d1 * d1) + (d2 * d2 + d3 * d3);
        }
#pragma unroll
        for (int o = 32; o > 0; o >>= 1) ss += __shfl_xor(ss, o, 64);
        const float var = ss * (1.0f / DIMIN);
        const float r = rsqrtf(var + 1e-5f);

        f16x8* qr = (f16x8*)(qA + (size_t)row * DIMIN);
#pragma unroll
        for (int j = 0; j < 4; ++j) {
            const float4 u0 = v[2 * j], u1 = v[2 * j + 1];
            f16x8 o;
            o[0] = (_Float16)((u0.x - mu) * r); o[1] = (_Float16)((u0.y - mu) * r);
            o[2] = (_Float16)((u0.z - mu) * r); o[3] = (_Float16)((u0.w - mu) * r);
            o[4] = (_Float16)((u1.x - mu) * r); o[5] = (_Float16)((u1.y - mu) * r);
            o[6] = (_Float16)((u1.z - mu) * r); o[7] = (_Float16)((u1.w - mu) * r);
            qr[ln + 64 * j] = o;
        }
    } else {
        const int p = b - NLNB;                  // 0..1023
        float acc = 0.0f;
        const float4* w4 = (const float4*)w;
        for (unsigned i = (unsigned)p * 256u + t; i < 4194304u; i += 262144u) {
            float4 v = w4[i];                    // 16 iterations
            acc += (fabsf(v.x) + fabsf(v.y)) + (fabsf(v.z) + fabsf(v.w));
        }
        __shared__ float shw[4];
#pragma unroll
        for (int o = 32; o > 0; o >>= 1) acc += __shfl_down(acc, o, 64);
        if ((t & 63) == 0) shw[t >> 6] = acc;
        __syncthreads();
        if (t == 0) wpart[p] = (shw[0] + shw[1]) + (shw[2] + shw[3]);
    }
}

// ---------------- K2: reduce partials, ternarize W to f16 -------------------
__global__ __launch_bounds__(256) void ternW_k(
    const float* __restrict__ w, const float* __restrict__ wpart,
    float* __restrict__ sc, _Float16* __restrict__ q) {
    const int t = threadIdx.x;
    __shared__ float sh[4];
    float4 p = ((const float4*)wpart)[t];        // 256 threads cover 1024 partials
    float acc = (p.x + p.y) + (p.z + p.w);
#pragma unroll
    for (int o = 32; o > 0; o >>= 1) acc += __shfl_down(acc, o, 64);
    if ((t & 63) == 0) sh[t >> 6] = acc;
    __syncthreads();
    const float wg = ((sh[0] + sh[1]) + (sh[2] + sh[3])) * (1.0f / W_ELEMS);
    if (blockIdx.x == 0 && t == 0) sc[0] = wg;   // for GEMM epilogue
    const float invw = 1.0f / (wg + 1e-7f);
    for (unsigned i = blockIdx.x * 256u + t; i < 4194304u; i += 262144u) {
        float4 v = ((const float4*)w)[i];        // 16 iterations (1024 blocks)
        f16x4 o;
        o.x = (_Float16)fminf(fmaxf(rintf(v.x * invw), -1.0f), 1.0f);
        o.y = (_Float16)fminf(fmaxf(rintf(v.y * invw), -1.0f), 1.0f);
        o.z = (_Float16)fminf(fmaxf(rintf(v.z * invw), -1.0f), 1.0f);
        o.w = (_Float16)fminf(fmaxf(rintf(v.w * invw), -1.0f), 1.0f);
        ((f16x4*)q)[i] = o;
    }
}

// ---------------- K3: deep-pipelined dual GEMM + SiLU gate ------------------
__device__ __forceinline__ void ld16(const _Float16* g, _Float16* l) {
    __builtin_amdgcn_global_load_lds(
        (const __attribute__((address_space(1))) unsigned int*)g,
        (__attribute__((address_space(3))) unsigned int*)l, 16, 0, 0);
}

// LDS map (f16 elems): B only. buf0 [0,16384) buf1 [16384,32768) = 64 KB.
// Buf rows 0..127 = W rows n0..n0+127 (h); rows 128..255 = n0+4096.. (g).
// Swizzle: logical (row, 16B-granule g) stored at granule g ^ (row&7);
// staging keeps LDS linear and pre-swizzles the GLOBAL source column.
// A never enters LDS: MFMA A-frag = 16B contiguous of row-major qA, loaded
// global->reg (L1/L2-served; A panel 1MB L2-resident per XCD via swizzle).
//
// Schedule per K-tile: phases (h,k0)(g,k0)(h,k1)(g,k1); all-B staging for
// t+1 issued at P0/P2 (2+2 global_load_lds); a0(t+1)/a1(t+1) reg-loads
// issued right after their last use (end P1 / end P3, 2-3 phases of cover).
// One barrier per tile: VMC(4) retires the 4 staging loads (+a0), keeps
// a1(t+1) in flight (compiler auto-waits reg loads before MFMA use).

#define BAR    __builtin_amdgcn_s_barrier()
#define SCHED0 __builtin_amdgcn_sched_barrier(0)
#define VMC(n) asm volatile("s_waitcnt vmcnt(" #n ")" ::: "memory")
#define PRIO1  __builtin_amdgcn_s_setprio(1)
#define PRIO0  __builtin_amdgcn_s_setprio(0)

#define MFMA16(AARR, ACC)                                                 \
    _Pragma("unroll") for (int mi = 0; mi < 4; ++mi)                      \
    _Pragma("unroll") for (int ni = 0; ni < 4; ++ni)                      \
        ACC[mi][ni] = __builtin_amdgcn_mfma_f32_16x16x32_f16(             \
            AARR[mi], b[ni], ACC[mi][ni], 0, 0, 0);

#define DSB(BOFF_)                                                        \
    _Pragma("unroll") for (int i = 0; i < 4; ++i)                         \
        b[i] = *(const f16x8*)(Bc + (BOFF_) + (i << 10));

__global__ __launch_bounds__(512, 4) void gemm_glu_k(
    const _Float16* __restrict__ Aq, const _Float16* __restrict__ Wq,
    const float* __restrict__ sc, float* __restrict__ out) {

    __shared__ __align__(16) _Float16 sm[32768];   // 64 KB (B double-buffer)

    const int tid  = threadIdx.x;
    const int wave = tid >> 6;
    const int lane = tid & 63;

    // bijective XCD swizzle (1024 % 8 == 0)
    const int swz = ((blockIdx.x & 7) << 7) + (blockIdx.x >> 3);
    const int m0 = (swz >> 5) << 8;   // tile row * 256
    const int n0 = (swz & 31) << 7;   // tile out-col * 128

    // --- B staging addresses (global source pre-swizzled, LDS dest linear) --
    const int rs = (wave << 3) + (lane >> 3);                  // row in 64-row stripe
    const int kc = (((lane & 7) ^ ((lane >> 3) & 7)) << 3);    // swizzled col
    const _Float16* pb = Wq + (size_t)(n0 + rs) * DIMIN + kc;

    // --- fragment geometry ---
    const int fr   = lane & 15;
    const int quad = lane >> 4;
    const int xr   = fr & 7;
    const int wm = (wave >> 1) << 6;   // 0,64,128,192
    const int wn = (wave & 1) << 6;    // 0,64
    const int b0off = (wn + fr) * 64 + ((quad ^ xr) << 3);         // k-slice 0
    const int b1off = (wn + fr) * 64 + (((quad + 4) ^ xr) << 3);   // k-slice 1
    // A direct-from-global: frag(mt, ks) at pa + mt*16*DIMIN + ks*32 + t*64
    const _Float16* pa = Aq + (size_t)(m0 + wm + fr) * DIMIN + quad * 8;

    const float s = sc[0];             // w_gamma (uniform scalar load, early)

    f32x4 z = {0.0f, 0.0f, 0.0f, 0.0f};
    f32x4 acc_h[4][4], acc_g[4][4];
#pragma unroll
    for (int i = 0; i < 4; ++i)
#pragma unroll
        for (int j = 0; j < 4; ++j) { acc_h[i][j] = z; acc_g[i][j] = z; }

    // ---- prologue: stage B(0) into buf0; load a0(0), a1(0) to regs ----
    {
        _Float16* dB = sm + (wave << 9);
        ld16(pb,                     dB);            // Bh rows 0-63
        ld16(pb + 131072,            dB + 4096);     // Bh rows 64-127
        ld16(pb + 8388608,           dB + 8192);     // Bg rows 0-63
        ld16(pb + 8388608 + 131072,  dB + 12288);    // Bg rows 64-127
        pb += 64;
    }
    f16x8 a0[4], a1[4], b[4];
#pragma unroll
    for (int i = 0; i < 4; ++i) a0[i] = *(const f16x8*)(pa + i * 32768);
#pragma unroll
    for (int i = 0; i < 4; ++i) a1[i] = *(const f16x8*)(pa + i * 32768 + 32);
    VMC(8);            // B(0) staged; a-reg loads tracked by compiler
    BAR; SCHED0;

    for (int t = 0; t < 31; ++t) {         // steady state: stages tile t+1
        const _Float16* Bc = sm + ((t & 1) << 14);
        _Float16* dB = sm + (((t + 1) & 1) << 14) + (wave << 9);
        const _Float16* pA = pa + t * 64 + 64;       // a(t+1) k-base

        // ---- P0: (h, k0) ----
        DSB(b0off);
        ld16(pb,          dB);                       // Bh(t+1) rows 0-63
        ld16(pb + 131072, dB + 4096);                // Bh(t+1) rows 64-127
        PRIO1; MFMA16(a0, acc_h); PRIO0;

        // ---- P1: (g, k0) -- last use of a0; then load a0(t+1) ----
        DSB(8192 + b0off);
        PRIO1; MFMA16(a0, acc_g); PRIO0;
#pragma unroll
        for (int i = 0; i < 4; ++i) a0[i] = *(const f16x8*)(pA + i * 32768);

        // ---- P2: (h, k1) ----
        DSB(b1off);
        ld16(pb + 8388608,          dB + 8192);      // Bg(t+1) rows 0-63
        ld16(pb + 8388608 + 131072, dB + 12288);     // Bg(t+1) rows 64-127
        PRIO1; MFMA16(a1, acc_h); PRIO0;

        // ---- P3: (g, k1) -- last use of a1; then load a1(t+1) ----
        DSB(8192 + b1off);
        PRIO1; MFMA16(a1, acc_g); PRIO0;
#pragma unroll
        for (int i = 0; i < 4; ++i) a1[i] = *(const f16x8*)(pA + i * 32768 + 32);

        VMC(4);        // retire 4 staging loads (+a0); keep a1(t+1) in flight
        BAR; SCHED0;

        pb += 64;
    }

    // ---- tail tile (t = 31, buf 1, no staging) ----
    {
        const _Float16* Bc = sm + 16384;

        DSB(b0off);
        PRIO1; MFMA16(a0, acc_h); PRIO0;

        DSB(8192 + b0off);
        PRIO1; MFMA16(a0, acc_g); PRIO0;

        DSB(b1off);
        PRIO1; MFMA16(a1, acc_h); PRIO0;

        DSB(8192 + b1off);
        PRIO1; MFMA16(a1, acc_g); PRIO0;
    }

    // ---- epilogue: GLU combine + store ----
    const int er = quad << 2;          // C/D: col = lane&15, row = quad*4 + r
#pragma unroll
    for (int mi = 0; mi < 4; ++mi)
#pragma unroll
        for (int ni = 0; ni < 4; ++ni)
#pragma unroll
            for (int r = 0; r < 4; ++r) {
                const int m = m0 + wm + (mi << 4) + er + r;
                const int n = n0 + wn + (ni << 4) + fr;
                const float h = acc_h[mi][ni][r] * s;
                const float g = acc_g[mi][ni][r] * s;
                out[(size_t)m * NOUT + n] = h * g / (1.0f + __expf(-g));
            }
}

// ---------------------------------------------------------------------------
extern "C" void kernel_launch(void* const* d_in, const int* in_sizes, int n_in,
                              void* d_out, int out_size, void* d_ws, size_t ws_size,
                              hipStream_t stream) {
    const float* x = (const float*)d_in[0];
    const float* w = (const float*)d_in[1];
    float* out = (float*)d_out;   // reference output dtype is float32

    char* ws = (char*)d_ws;
    float* sc    = (float*)ws;                                // [0] = wg
    float* wpart = (float*)(ws + 4096);                       // 1024 partials
    _Float16* qA = (_Float16*)(ws + 16384);                   // 32 MB normed f16
    _Float16* wB = (_Float16*)(ws + 16384 + 33554432);        // 32 MB ternary f16

    ln_wsum_k<<<NLNB + NPART, 256, 0, stream>>>(x, w, qA, wpart);
    ternW_k<<<NPART, 256, 0, stream>>>(w, wpart, sc, wB);

    gemm_glu_k<<<dim3(1024), dim3(512), 0, stream>>>(qA, wB, sc, out);
}